// Round 1
// baseline (215.955 us; speedup 1.0000x reference)
//
#include <hip/hip_runtime.h>
#include <hip/hip_bf16.h>
#include <math.h>

// Problem constants (fixed by reference: b=2, h=w=64, dim=256, attn_dim=128, HEAD=4)
#define N_TOK 4096   // h*w
#define C_DIM 256
#define A_DIM 128
#define HEADS 4
#define HD    32     // head_dim
#define NBAT  2
#define BH    (NBAT * HEADS)

// scale * log2(e) = (1/sqrt(32)) * 1.4426950408889634
#define SCALE_LOG2E 0.2550352f

typedef __attribute__((ext_vector_type(8))) short short8;   // 8 bf16 = one MFMA A/B frag
typedef __attribute__((ext_vector_type(4))) float floatx4;  // one MFMA C/D frag

__device__ __forceinline__ unsigned short f2bf(float f) {
    // round-to-nearest-even fp32 -> bf16
    unsigned int u = __float_as_uint(f);
    u = (u + 0x7fffu + ((u >> 16) & 1u)) >> 16;
    return (unsigned short)u;
}

// ---------------------------------------------------------------------------
// K1: fused QKV projection. rows = [b*n] = 8192 of query/context (256 cols).
// Q,K out: bf16 [bh][n][32]  (A/B-frag friendly: 16B contiguous per (row, quad))
// V out:   bf16 [bh][32][n]  (transposed so PV B-frags are contiguous in key)
// block = 128 threads (thread t owns output column t of Wq/Wk/Wv), 8 rows/block
// ---------------------------------------------------------------------------
__global__ __launch_bounds__(128) void qkv_kernel(
    const float* __restrict__ query, const float* __restrict__ context,
    const float* __restrict__ Wq, const float* __restrict__ Wk,
    const float* __restrict__ Wv,
    unsigned short* __restrict__ Qb, unsigned short* __restrict__ Kb,
    unsigned short* __restrict__ Vb)
{
    __shared__ __align__(16) float qr[8][C_DIM];
    __shared__ __align__(16) float cr[8][C_DIM];
    const int tid = threadIdx.x;
    const long row0 = (long)blockIdx.x * 8;

    // stage 8 rows of query + context (2048 floats each), float4 loads
    for (int i = tid; i < 8 * (C_DIM / 4); i += 128) {
        const int r = i >> 6;       // 64 float4 per row
        const int c4 = i & 63;
        ((floatx4*)qr[r])[c4] = ((const floatx4*)(query + (row0 + r) * C_DIM))[c4];
        ((floatx4*)cr[r])[c4] = ((const floatx4*)(context + (row0 + r) * C_DIM))[c4];
    }
    __syncthreads();

    float aq[8] = {}, ak[8] = {}, av[8] = {};
    for (int kk = 0; kk < C_DIM; kk += 4) {
        floatx4 wq4, wk4, wv4;
        #pragma unroll
        for (int u = 0; u < 4; u++) {
            wq4[u] = Wq[(kk + u) * A_DIM + tid];   // coalesced across threads
            wk4[u] = Wk[(kk + u) * A_DIM + tid];
            wv4[u] = Wv[(kk + u) * A_DIM + tid];
        }
        #pragma unroll
        for (int r = 0; r < 8; r++) {
            floatx4 q4 = *(floatx4*)&qr[r][kk];   // b128 broadcast reads
            floatx4 c4 = *(floatx4*)&cr[r][kk];
            #pragma unroll
            for (int u = 0; u < 4; u++) {
                aq[r] = fmaf(q4[u], wq4[u], aq[r]);
                ak[r] = fmaf(c4[u], wk4[u], ak[r]);
                av[r] = fmaf(c4[u], wv4[u], av[r]);
            }
        }
    }

    const int h = tid >> 5;        // head of this output column
    const int d = tid & 31;        // dim within head
    const long b = row0 >> 12;     // 4096 rows per batch
    const long nrow = row0 & (N_TOK - 1);
    const long bh = b * HEADS + h;

    unsigned short* qdst = Qb + (bh * N_TOK + nrow) * HD + d;
    unsigned short* kdst = Kb + (bh * N_TOK + nrow) * HD + d;
    #pragma unroll
    for (int r = 0; r < 8; r++) {
        qdst[r * HD] = f2bf(aq[r]);
        kdst[r * HD] = f2bf(ak[r]);
    }
    // V transposed: 8 consecutive rows for fixed d are contiguous -> one 16B store
    short8 vv;
    #pragma unroll
    for (int r = 0; r < 8; r++) vv[r] = (short)f2bf(av[r]);
    *(short8*)(Vb + (bh * HD + d) * N_TOK + nrow) = vv;
}

// ---------------------------------------------------------------------------
// K2: flash attention, no-max softmax (scores bounded; direct sum of exp).
// 1 wave = 16 queries; block = 4 waves = 64 queries; grid (64 qtiles, 8 bh).
// Per 64-key tile: stage K [key][dim] + V^T [dim][key] in LDS; per 32-key sub:
//   S = Q*K^T (2 MFMA) -> exp2 -> P (bf16) -> wave-private LDS round-trip to
//   A-layout -> PV (2 MFMA) accumulating fp32.
// ---------------------------------------------------------------------------
__global__ __launch_bounds__(256) void attn_kernel(
    const unsigned short* __restrict__ Qb, const unsigned short* __restrict__ Kb,
    const unsigned short* __restrict__ Vb, float* __restrict__ AO)
{
    __shared__ __align__(16) unsigned short K_lds[64 * HD];    // [key][dim] 4KB
    __shared__ __align__(16) unsigned short V_lds[HD * 64];    // [dim][key] 4KB
    __shared__ __align__(16) unsigned short P_lds[4][16 * 32]; // per-wave scratch

    const int tid  = threadIdx.x;
    const int w    = tid >> 6;
    const int lane = tid & 63;
    const int quad = lane >> 4;
    const int l15  = lane & 15;
    const int bh   = blockIdx.y;
    const int i0   = blockIdx.x * 64 + w * 16;   // first query of this wave

    const unsigned short* Qh = Qb + (long)bh * N_TOK * HD;
    const unsigned short* Kh = Kb + (long)bh * N_TOK * HD;
    const unsigned short* Vh = Vb + (long)bh * HD * N_TOK;

    // Q A-frag: A[m = l15][k = quad*8 + jj] -> contiguous 16B per lane
    const short8 qfrag = *(const short8*)(Qh + (long)(i0 + l15) * HD + quad * 8);

    floatx4 acc0 = {0.f, 0.f, 0.f, 0.f};   // out dims 0..15   (C layout)
    floatx4 acc1 = {0.f, 0.f, 0.f, 0.f};   // out dims 16..31
    floatx4 lpart = {0.f, 0.f, 0.f, 0.f};  // softmax denom partials, rows quad*4+r

    for (int j0 = 0; j0 < N_TOK; j0 += 64) {
        __syncthreads();   // previous tile fully consumed
        // stage K tile: 64 keys x 32 dims = 4KB; 256 threads x 16B, lane-linear
        *(short8*)&K_lds[tid * 8] = *(const short8*)(Kh + (long)j0 * HD + tid * 8);
        // stage V^T tile: dims 0..31 x keys j0..j0+63; tid -> d = tid>>3, chunk = tid&7
        *(short8*)&V_lds[tid * 8] =
            *(const short8*)(Vh + (long)(tid >> 3) * N_TOK + j0 + (tid & 7) * 8);
        __syncthreads();

        #pragma unroll
        for (int sub = 0; sub < 2; sub++) {
            const int jb = sub * 32;
            // K B-frags: B[k=dim quad*8+jj][n=key l15 (+16)] = K[j0+jb+n][k]
            short8 kf0 = *(short8*)&K_lds[(jb + l15) * HD + quad * 8];
            short8 kf1 = *(short8*)&K_lds[(jb + 16 + l15) * HD + quad * 8];
            floatx4 z = {0.f, 0.f, 0.f, 0.f};
            floatx4 s0 = __builtin_amdgcn_mfma_f32_16x16x32_bf16(qfrag, kf0, z, 0, 0, 0);
            floatx4 s1 = __builtin_amdgcn_mfma_f32_16x16x32_bf16(qfrag, kf1, z, 0, 0, 0);

            // p = exp(s * scale) = 2^(s * scale * log2e); accumulate denominator
            floatx4 p0, p1;
            #pragma unroll
            for (int r = 0; r < 4; r++) {
                p0[r] = exp2f(s0[r] * SCALE_LOG2E);
                p1[r] = exp2f(s1[r] * SCALE_LOG2E);
                lpart[r] += p0[r] + p1[r];
            }

            // C-layout (row=quad*4+r, col=l15 / l15+16) -> LDS -> A-layout
            unsigned short* Pw = P_lds[w];   // wave-private: no barrier needed
            #pragma unroll
            for (int r = 0; r < 4; r++) {
                Pw[(quad * 4 + r) * 32 + l15]      = f2bf(p0[r]);
                Pw[(quad * 4 + r) * 32 + 16 + l15] = f2bf(p1[r]);
            }
            short8 pfrag = *(short8*)&Pw[l15 * 32 + quad * 8];

            // V B-frags: B[k=key quad*8+jj][n=dim l15 (+16)] = V^T[n][j0+jb+k]
            short8 vf0 = *(short8*)&V_lds[l15 * 64 + jb + quad * 8];
            short8 vf1 = *(short8*)&V_lds[(16 + l15) * 64 + jb + quad * 8];
            acc0 = __builtin_amdgcn_mfma_f32_16x16x32_bf16(pfrag, vf0, acc0, 0, 0, 0);
            acc1 = __builtin_amdgcn_mfma_f32_16x16x32_bf16(pfrag, vf1, acc1, 0, 0, 0);
        }
    }

    // reduce denom across the 16 lanes of each quad (cols of the C tile)
    #pragma unroll
    for (int off = 1; off < 16; off <<= 1) {
        #pragma unroll
        for (int r = 0; r < 4; r++) lpart[r] += __shfl_xor(lpart[r], off);
    }

    // write normalized output: AO fp32 [b][n][A_DIM], head h occupies cols h*32..+31
    const int b = bh >> 2, h = bh & 3;
    #pragma unroll
    for (int r = 0; r < 4; r++) {
        const float inv = 1.0f / lpart[r];
        const long row = (long)b * N_TOK + i0 + quad * 4 + r;
        AO[row * A_DIM + h * HD + l15]      = acc0[r] * inv;
        AO[row * A_DIM + h * HD + 16 + l15] = acc1[r] * inv;
    }
}

// ---------------------------------------------------------------------------
// K3: out-projection fp32: [8192,128] @ Wo[128,256] -> out [8192,256]
// block = 256 threads (thread t owns out column t), 8 rows/block
// ---------------------------------------------------------------------------
__global__ __launch_bounds__(256) void outproj_kernel(
    const float* __restrict__ AO, const float* __restrict__ Wo,
    float* __restrict__ out)
{
    __shared__ __align__(16) float a_lds[8][A_DIM];
    const int tid = threadIdx.x;
    const long row0 = (long)blockIdx.x * 8;

    for (int i = tid; i < 8 * (A_DIM / 4); i += 256) {   // 256 float4 total
        const int r = i >> 5, c4 = i & 31;
        ((floatx4*)a_lds[r])[c4] = ((const floatx4*)(AO + (row0 + r) * A_DIM))[c4];
    }
    __syncthreads();

    float acc[8] = {};
    for (int kk = 0; kk < A_DIM; kk += 4) {
        floatx4 w4;
        #pragma unroll
        for (int u = 0; u < 4; u++) w4[u] = Wo[(kk + u) * C_DIM + tid];
        #pragma unroll
        for (int r = 0; r < 8; r++) {
            floatx4 a4 = *(floatx4*)&a_lds[r][kk];
            #pragma unroll
            for (int u = 0; u < 4; u++) acc[r] = fmaf(a4[u], w4[u], acc[r]);
        }
    }
    #pragma unroll
    for (int r = 0; r < 8; r++) out[(row0 + r) * C_DIM + tid] = acc[r];
}

// ---------------------------------------------------------------------------
extern "C" void kernel_launch(void* const* d_in, const int* in_sizes, int n_in,
                              void* d_out, int out_size, void* d_ws, size_t ws_size,
                              hipStream_t stream)
{
    const float* query   = (const float*)d_in[0];
    const float* context = (const float*)d_in[1];
    const float* Wq      = (const float*)d_in[2];
    const float* Wk      = (const float*)d_in[3];
    const float* Wv      = (const float*)d_in[4];
    const float* Wo      = (const float*)d_in[5];
    float* out = (float*)d_out;

    char* ws = (char*)d_ws;
    unsigned short* Qb = (unsigned short*)(ws);              // 2 MB  [bh][n][32] bf16
    unsigned short* Kb = (unsigned short*)(ws + (2 << 20));  // 2 MB  [bh][n][32] bf16
    unsigned short* Vb = (unsigned short*)(ws + (4 << 20));  // 2 MB  [bh][32][n] bf16
    float*          AO = (float*)(ws + (6 << 20));           // 4 MB  [b*n][128] fp32

    qkv_kernel<<<dim3(8192 / 8), dim3(128), 0, stream>>>(query, context, Wq, Wk, Wv,
                                                         Qb, Kb, Vb);
    attn_kernel<<<dim3(N_TOK / 64, BH), dim3(256), 0, stream>>>(Qb, Kb, Vb, AO);
    outproj_kernel<<<dim3(8192 / 8), dim3(256), 0, stream>>>(AO, Wo, out);
}